// Round 3
// baseline (70.430 us; speedup 1.0000x reference)
//
#include <hip/hip_runtime.h>

// B=64, D=256, M=100
//   k(b,i,j) = 0.5 * sum_m (|f_i+f_j| - |f_i-f_j|) * exp(T)
//   out = k - rowmean_i - rowmean_j (symmetric), triu-packed per batch.
// VALU-bound (not bilinear -> no MFMA). Pass1: partial 64x64 tiles, 8x4 regs
// per thread, split-M 50/50. Pass2: combine + center + pack.

#define NB 64
#define DD 256
#define MM 100
#define TILE 64
#define NUT 10                 // upper 64x64 tile-pairs of the 4x4 tile grid
#define TRI_PER_B 32896        // D*(D+1)/2
#define NTILE 640              // NB * NUT
#define NMH 50                 // M-half
#define TILE_F (TILE * TILE)

__device__ __forceinline__ void tile_coords(int t, int& ti, int& tj) {
    int a = (t >= 4) + (t >= 7) + (t >= 9);
    int s = (a * (9 - a)) >> 1;   // 0,4,7,9
    ti = a;
    tj = t - s + a;
}

// Pass 1: one M-half of one 64x64 tile per block. 128 threads, 8x4 regs each.
extern "C" __global__ void __launch_bounds__(128, 4)
k_partial(const float* __restrict__ f, float* __restrict__ rows,
          float* __restrict__ tiles, int atomic_mode) {
    __shared__ float As[NMH][TILE];   // 12.5 KB, [m][row] layout
    __shared__ float Bs[NMH][TILE];
    const int t = threadIdx.x;
    const int bid = blockIdx.x;       // 0..1279
    const int h = bid & 1;            // M-half
    const int bt = bid >> 1;          // tile id 0..639
    const int b = bt / NUT;
    const int ut = bt % NUT;
    int ti, tj;
    tile_coords(ut, ti, tj);
    const int i0 = ti * TILE, j0 = tj * TILE;
    const float* fb = f + (size_t)b * DD * MM + h * NMH;

    // Stage both operand tiles. Lanes span rows within one inst -> LDS writes
    // conflict-free ([m][row], bank = row%32, 2-way = free).
    for (int l = t; l < TILE * (NMH / 2); l += 128) {   // 1600 float2
        const int il = l & 63;
        const int m2 = l >> 6;                          // 0..24
        float2 v = *reinterpret_cast<const float2*>(fb + (size_t)(i0 + il) * MM + m2 * 2);
        As[m2 * 2 + 0][il] = v.x;
        As[m2 * 2 + 1][il] = v.y;
        float2 w = *reinterpret_cast<const float2*>(fb + (size_t)(j0 + il) * MM + m2 * 2);
        Bs[m2 * 2 + 0][il] = w.x;
        Bs[m2 * 2 + 1][il] = w.y;
    }
    __syncthreads();

    const int tix = t & 7;     // row group: rows tix*8 .. +7
    const int tiy = t >> 3;    // col group: cols tiy*4 .. +3   (0..15)
    float acc[8][4] = {};
    #pragma unroll 10
    for (int m = 0; m < NMH; ++m) {
        float4 a0 = *reinterpret_cast<const float4*>(&As[m][tix * 8]);
        float4 a1 = *reinterpret_cast<const float4*>(&As[m][tix * 8 + 4]);
        float4 b4 = *reinterpret_cast<const float4*>(&Bs[m][tiy * 4]);
        float av[8] = {a0.x, a0.y, a0.z, a0.w, a1.x, a1.y, a1.z, a1.w};
        float bv[4] = {b4.x, b4.y, b4.z, b4.w};
        #pragma unroll
        for (int q = 0; q < 8; ++q) {
            #pragma unroll
            for (int r = 0; r < 4; ++r) {
                float s = av[q] + bv[r];
                float d = av[q] - bv[r];
                acc[q][r] += fabsf(s) - fabsf(d);   // abs -> input modifiers
            }
        }
    }

    // partial tile -> workspace (row-major [row][col])
    if (atomic_mode) {
        float* tp = tiles + (size_t)bt * TILE_F;
        #pragma unroll
        for (int q = 0; q < 8; ++q)
            #pragma unroll
            for (int r = 0; r < 4; ++r)
                atomicAdd(tp + (tix * 8 + q) * TILE + tiy * 4 + r, acc[q][r]);
    } else {
        float* tp = tiles + ((size_t)h * NTILE + bt) * TILE_F;
        #pragma unroll
        for (int q = 0; q < 8; ++q) {
            float4 v = make_float4(acc[q][0], acc[q][1], acc[q][2], acc[q][3]);
            *reinterpret_cast<float4*>(tp + (tix * 8 + q) * TILE + tiy * 4) = v;
        }
    }

    // row sums (and symmetric col sums for off-diagonal tiles)
    float ra[8], cb[4];
    #pragma unroll
    for (int q = 0; q < 8; ++q)
        ra[q] = (acc[q][0] + acc[q][1]) + (acc[q][2] + acc[q][3]);
    #pragma unroll
    for (int r = 0; r < 4; ++r)
        cb[r] = ((acc[0][r] + acc[1][r]) + (acc[2][r] + acc[3][r]))
              + ((acc[4][r] + acc[5][r]) + (acc[6][r] + acc[7][r]));

    __syncthreads();                       // done reading As/Bs; reuse as scratch
    float* red  = &As[0][0];               // [16][64] row contributions
    float* red2 = &Bs[0][0];               // [8][64]  col contributions
    #pragma unroll
    for (int q = 0; q < 8; ++q) red[tiy * 64 + tix * 8 + q] = ra[q];
    #pragma unroll
    for (int r = 0; r < 4; ++r) red2[tix * 64 + tiy * 4 + r] = cb[r];
    __syncthreads();

    if (t < TILE) {
        float s = 0.f;
        #pragma unroll
        for (int w = 0; w < 16; ++w) s += red[w * 64 + t];
        atomicAdd(&rows[b * DD + i0 + t], s);
    } else if (ti != tj) {
        const int u = t - TILE;
        float s = 0.f;
        #pragma unroll
        for (int w = 0; w < 8; ++w) s += red2[w * 64 + u];
        atomicAdd(&rows[b * DD + j0 + u], s);
    }
}

// Pass 2: combine slices, center, scale, triu-pack. No LDS, coalesced.
extern "C" __global__ void __launch_bounds__(256)
k_finalize(const float* __restrict__ rows, const float* __restrict__ temp,
           const float* __restrict__ tiles, int nslice, float* __restrict__ out) {
    const int t = threadIdx.x;
    const int bt = blockIdx.x;        // 0..639
    const int b = bt / NUT;
    const int ut = bt % NUT;
    int ti, tj;
    tile_coords(ut, ti, tj);
    const int i0 = ti * TILE, j0 = tj * TILE;
    const int tix = t >> 4, tiy = t & 15;

    const float* t0 = tiles + (size_t)bt * TILE_F;
    const float* t1 = tiles + ((size_t)NTILE + bt) * TILE_F;

    float acc[4][4];
    #pragma unroll
    for (int q = 0; q < 4; ++q) {
        const int off = (tix * 4 + q) * TILE + tiy * 4;
        float4 v = *reinterpret_cast<const float4*>(t0 + off);
        acc[q][0] = v.x; acc[q][1] = v.y; acc[q][2] = v.z; acc[q][3] = v.w;
        if (nslice == 2) {
            float4 w = *reinterpret_cast<const float4*>(t1 + off);
            acc[q][0] += w.x; acc[q][1] += w.y; acc[q][2] += w.z; acc[q][3] += w.w;
        }
    }

    const float scale = 0.5f * expf(temp[0]);
    const float inv_d = 1.0f / DD;
    float rloc[4], cloc[4];
    #pragma unroll
    for (int q = 0; q < 4; ++q) rloc[q] = rows[b * DD + i0 + tix * 4 + q];
    #pragma unroll
    for (int r = 0; r < 4; ++r) cloc[r] = rows[b * DD + j0 + tiy * 4 + r];

    float* ob = out + (size_t)b * TRI_PER_B;
    #pragma unroll
    for (int q = 0; q < 4; ++q) {
        const int i = i0 + tix * 4 + q;
        float v[4];
        #pragma unroll
        for (int r = 0; r < 4; ++r)
            v[r] = scale * (acc[q][r] - (rloc[q] + cloc[r]) * inv_d);
        const int j0e = j0 + tiy * 4;
        if (ti != tj) {
            const int off = (i * (2 * DD - i + 1)) / 2 + (j0e - i);
            *reinterpret_cast<float4*>(ob + off) = make_float4(v[0], v[1], v[2], v[3]);
        } else {
            #pragma unroll
            for (int r = 0; r < 4; ++r) {
                const int j = j0e + r;
                if (j >= i) {
                    const int off = (i * (2 * DD - i + 1)) / 2 + (j - i);
                    ob[off] = v[r];
                }
            }
        }
    }
}

extern "C" void kernel_launch(void* const* d_in, const int* in_sizes, int n_in,
                              void* d_out, int out_size, void* d_ws, size_t ws_size,
                              hipStream_t stream) {
    const float* f    = (const float*)d_in[0];
    const float* temp = (const float*)d_in[1];
    float* out  = (float*)d_out;
    float* rows = (float*)d_ws;                       // 64 KB
    float* tiles = rows + NB * DD;

    const size_t rows_b = (size_t)NB * DD * sizeof(float);
    const size_t tile_b = (size_t)NTILE * TILE_F * sizeof(float);  // 10.5 MB
    const size_t need2  = rows_b + 2 * tile_b;                     // 21.0 MB

    hipMemsetAsync(rows, 0, rows_b, stream);
    if (ws_size >= need2) {
        k_partial<<<2 * NTILE, 128, 0, stream>>>(f, rows, tiles, 0);
        k_finalize<<<NTILE, 256, 0, stream>>>(rows, temp, tiles, 2, out);
    } else {
        hipMemsetAsync(tiles, 0, tile_b, stream);
        k_partial<<<2 * NTILE, 128, 0, stream>>>(f, rows, tiles, 1);
        k_finalize<<<NTILE, 256, 0, stream>>>(rows, temp, tiles, 1, out);
    }
}

// Round 4
// 58.616 us; speedup vs baseline: 1.2015x; 1.2015x over previous
//
#include <hip/hip_runtime.h>

// B=64, D=256, M=100
//   k(b,i,j) = 0.5 * sum_m (|f_i+f_j| - |f_i-f_j|) * exp(T)
//   out = k - rowmean_i - rowmean_j (symmetric), triu-packed per batch.
// VALU-bound (not bilinear -> no MFMA). Pass1: 64x64 tiles, 256 thr, 4x4/thread,
// split-M 50/50, packed-f32 (v_pk_add_f32) inner loop + prefetch pipeline.
// Pass2: combine halves + center + pack.

#define NB 64
#define DD 256
#define MM 100
#define TILE 64
#define NUT 10                 // upper 64x64 tile-pairs of the 4x4 tile grid
#define TRI_PER_B 32896        // D*(D+1)/2
#define NTILE 640              // NB * NUT
#define NMH 50                 // M-half
#define TILE_F (TILE * TILE)

typedef float f32x2 __attribute__((ext_vector_type(2)));

__device__ __forceinline__ void tile_coords(int t, int& ti, int& tj) {
    int a = (t >= 4) + (t >= 7) + (t >= 9);
    int s = (a * (9 - a)) >> 1;   // 0,4,7,9
    ti = a;
    tj = t - s + a;
}

// one m-step of the 4x4 micro-tile, packed-f32 formulation
__device__ __forceinline__ void pair_step(const float4& af, const float4& bf,
                                          f32x2 acc2[2][4]) {
    f32x2 a01; a01.x = af.x; a01.y = af.y;
    f32x2 a23; a23.x = af.z; a23.y = af.w;
    const float bvals[4] = {bf.x, bf.y, bf.z, bf.w};
    #pragma unroll
    for (int r = 0; r < 4; ++r) {
        f32x2 bb; bb.x = bvals[r]; bb.y = bvals[r];
        f32x2 s0 = a01 + bb;      // v_pk_add_f32
        f32x2 d0 = a01 - bb;      // v_pk_add_f32 (neg mods)
        f32x2 s1 = a23 + bb;
        f32x2 d1 = a23 - bb;
        f32x2 t0, t1;
        t0.x = fabsf(s0.x) - fabsf(d0.x);   // v_sub_f32 |s|,|d| (abs mods)
        t0.y = fabsf(s0.y) - fabsf(d0.y);
        t1.x = fabsf(s1.x) - fabsf(d1.x);
        t1.y = fabsf(s1.y) - fabsf(d1.y);
        acc2[0][r] += t0;         // v_pk_add_f32
        acc2[1][r] += t1;
    }
}

// Pass 1: one M-half of one 64x64 tile per block.
extern "C" __global__ void __launch_bounds__(256, 5)
k_partial(const float* __restrict__ f, float* __restrict__ rows,
          float* __restrict__ tiles, int atomic_mode) {
    __shared__ float As[NMH][TILE];   // 12.5 KB, [m][row]
    __shared__ float Bs[NMH][TILE];
    const int t = threadIdx.x;
    const int bid = blockIdx.x;       // 0..1279
    const int h = bid & 1;            // M-half
    const int bt = bid >> 1;          // tile id 0..639
    const int b = bt / NUT;
    const int ut = bt % NUT;
    int ti, tj;
    tile_coords(ut, ti, tj);
    const int i0 = ti * TILE, j0 = tj * TILE;
    const float* fb = f + (size_t)b * DD * MM + h * NMH;

    // Stage [m][row] tiles; LDS writes 2-way/bank (free).
    for (int l = t; l < TILE * (NMH / 2); l += 256) {   // 1600 float2
        const int il = l & 63;
        const int m2 = l >> 6;                          // 0..24
        float2 v = *reinterpret_cast<const float2*>(fb + (size_t)(i0 + il) * MM + m2 * 2);
        As[m2 * 2 + 0][il] = v.x;
        As[m2 * 2 + 1][il] = v.y;
        float2 w = *reinterpret_cast<const float2*>(fb + (size_t)(j0 + il) * MM + m2 * 2);
        Bs[m2 * 2 + 0][il] = w.x;
        Bs[m2 * 2 + 1][il] = w.y;
    }
    __syncthreads();

    const int tix = t & 15, tiy = t >> 4;
    f32x2 acc2[2][4];   // acc[q][r] = acc2[q>>1][r][q&1]
    #pragma unroll
    for (int p = 0; p < 2; ++p)
        #pragma unroll
        for (int r = 0; r < 4; ++r) { acc2[p][r].x = 0.f; acc2[p][r].y = 0.f; }

    // software-pipelined m-loop: prefetch m+1 fragments while computing m
    float4 af = *reinterpret_cast<const float4*>(&As[0][tix * 4]);
    float4 bf = *reinterpret_cast<const float4*>(&Bs[0][tiy * 4]);
    #pragma unroll 2
    for (int m = 0; m < NMH - 1; ++m) {
        float4 an = *reinterpret_cast<const float4*>(&As[m + 1][tix * 4]);
        float4 bn = *reinterpret_cast<const float4*>(&Bs[m + 1][tiy * 4]);
        pair_step(af, bf, acc2);
        af = an; bf = bn;
    }
    pair_step(af, bf, acc2);

    // partial tile -> workspace (row-major [row][col])
    if (atomic_mode) {
        float* tp = tiles + (size_t)bt * TILE_F;
        #pragma unroll
        for (int p = 0; p < 2; ++p)
            #pragma unroll
            for (int e = 0; e < 2; ++e) {
                const int q = p * 2 + e;
                #pragma unroll
                for (int r = 0; r < 4; ++r)
                    atomicAdd(tp + (tix * 4 + q) * TILE + tiy * 4 + r,
                              e ? acc2[p][r].y : acc2[p][r].x);
            }
    } else {
        float* tp = tiles + ((size_t)h * NTILE + bt) * TILE_F;
        #pragma unroll
        for (int p = 0; p < 2; ++p)
            #pragma unroll
            for (int e = 0; e < 2; ++e) {
                const int q = p * 2 + e;
                float4 v;
                v.x = e ? acc2[p][0].y : acc2[p][0].x;
                v.y = e ? acc2[p][1].y : acc2[p][1].x;
                v.z = e ? acc2[p][2].y : acc2[p][2].x;
                v.w = e ? acc2[p][3].y : acc2[p][3].x;
                *reinterpret_cast<float4*>(tp + (tix * 4 + q) * TILE + tiy * 4) = v;
            }
    }

    // row sums (and symmetric col sums for off-diagonal tiles)
    float ra[4], cb[4];
    #pragma unroll
    for (int p = 0; p < 2; ++p) {
        ra[p * 2 + 0] = (acc2[p][0].x + acc2[p][1].x) + (acc2[p][2].x + acc2[p][3].x);
        ra[p * 2 + 1] = (acc2[p][0].y + acc2[p][1].y) + (acc2[p][2].y + acc2[p][3].y);
    }
    #pragma unroll
    for (int r = 0; r < 4; ++r) {
        f32x2 c2 = acc2[0][r] + acc2[1][r];
        cb[r] = c2.x + c2.y;
    }

    __syncthreads();                       // reuse As/Bs as scratch
    float* red  = &As[0][0];               // [16][64] row contributions
    float* red2 = &Bs[0][0];               // [16][64] col contributions
    #pragma unroll
    for (int q = 0; q < 4; ++q) red[tiy * 64 + tix * 4 + q] = ra[q];
    #pragma unroll
    for (int r = 0; r < 4; ++r) red2[tix * 64 + tiy * 4 + r] = cb[r];
    __syncthreads();

    if (t < TILE) {
        float s = 0.f;
        #pragma unroll
        for (int w = 0; w < 16; ++w) s += red[w * 64 + t];
        atomicAdd(&rows[b * DD + i0 + t], s);
    } else if (t < 2 * TILE && ti != tj) {
        const int u = t - TILE;
        float s = 0.f;
        #pragma unroll
        for (int w = 0; w < 16; ++w) s += red2[w * 64 + u];
        atomicAdd(&rows[b * DD + j0 + u], s);
    }
}

// Pass 2: combine slices, center, scale, triu-pack. No LDS, coalesced.
extern "C" __global__ void __launch_bounds__(256)
k_finalize(const float* __restrict__ rows, const float* __restrict__ temp,
           const float* __restrict__ tiles, int nslice, float* __restrict__ out) {
    const int t = threadIdx.x;
    const int bt = blockIdx.x;        // 0..639
    const int b = bt / NUT;
    const int ut = bt % NUT;
    int ti, tj;
    tile_coords(ut, ti, tj);
    const int i0 = ti * TILE, j0 = tj * TILE;
    const int tix = t >> 4, tiy = t & 15;

    const float* t0 = tiles + (size_t)bt * TILE_F;
    const float* t1 = tiles + ((size_t)NTILE + bt) * TILE_F;

    float acc[4][4];
    #pragma unroll
    for (int q = 0; q < 4; ++q) {
        const int off = (tix * 4 + q) * TILE + tiy * 4;
        float4 v = *reinterpret_cast<const float4*>(t0 + off);
        acc[q][0] = v.x; acc[q][1] = v.y; acc[q][2] = v.z; acc[q][3] = v.w;
        if (nslice == 2) {
            float4 w = *reinterpret_cast<const float4*>(t1 + off);
            acc[q][0] += w.x; acc[q][1] += w.y; acc[q][2] += w.z; acc[q][3] += w.w;
        }
    }

    const float scale = 0.5f * expf(temp[0]);
    const float inv_d = 1.0f / DD;
    float rloc[4], cloc[4];
    #pragma unroll
    for (int q = 0; q < 4; ++q) rloc[q] = rows[b * DD + i0 + tix * 4 + q];
    #pragma unroll
    for (int r = 0; r < 4; ++r) cloc[r] = rows[b * DD + j0 + tiy * 4 + r];

    float* ob = out + (size_t)b * TRI_PER_B;
    #pragma unroll
    for (int q = 0; q < 4; ++q) {
        const int i = i0 + tix * 4 + q;
        float v[4];
        #pragma unroll
        for (int r = 0; r < 4; ++r)
            v[r] = scale * (acc[q][r] - (rloc[q] + cloc[r]) * inv_d);
        const int j0e = j0 + tiy * 4;
        if (ti != tj) {
            const int off = (i * (2 * DD - i + 1)) / 2 + (j0e - i);
            *reinterpret_cast<float4*>(ob + off) = make_float4(v[0], v[1], v[2], v[3]);
        } else {
            #pragma unroll
            for (int r = 0; r < 4; ++r) {
                const int j = j0e + r;
                if (j >= i) {
                    const int off = (i * (2 * DD - i + 1)) / 2 + (j - i);
                    ob[off] = v[r];
                }
            }
        }
    }
}

extern "C" void kernel_launch(void* const* d_in, const int* in_sizes, int n_in,
                              void* d_out, int out_size, void* d_ws, size_t ws_size,
                              hipStream_t stream) {
    const float* f    = (const float*)d_in[0];
    const float* temp = (const float*)d_in[1];
    float* out  = (float*)d_out;
    float* rows = (float*)d_ws;                       // 64 KB
    float* tiles = rows + NB * DD;

    const size_t rows_b = (size_t)NB * DD * sizeof(float);
    const size_t tile_b = (size_t)NTILE * TILE_F * sizeof(float);  // 10.5 MB
    const size_t need2  = rows_b + 2 * tile_b;                     // 21.0 MB

    hipMemsetAsync(rows, 0, rows_b, stream);
    if (ws_size >= need2) {
        k_partial<<<2 * NTILE, 256, 0, stream>>>(f, rows, tiles, 0);
        k_finalize<<<NTILE, 256, 0, stream>>>(rows, temp, tiles, 2, out);
    } else {
        hipMemsetAsync(tiles, 0, tile_b, stream);
        k_partial<<<2 * NTILE, 256, 0, stream>>>(f, rows, tiles, 1);
        k_finalize<<<NTILE, 256, 0, stream>>>(rows, temp, tiles, 1, out);
    }
}

// Round 6
// 43.467 us; speedup vs baseline: 1.6203x; 1.3485x over previous
//
#include <hip/hip_runtime.h>

// B=64, D=256, M=100
//   k(b,i,j) = 0.5 * sum_m (|f_i+f_j| - |f_i-f_j|) * exp(T)
//            = sum_m sign(f_i)sign(f_j)min(|f_i|,|f_j|) * exp(T)   [0.5 absorbed]
//   out = k - rowmean_i - rowmean_j (symmetric), triu-packed per batch.
// VALU-bound (not bilinear -> no MFMA). Inner loop: packed fp16 min + sign-xor
// + v_dot2_f32_f16 accumulate (f32 accumulator, exact products).
// Split-M 50/50 -> 1280 blocks. Pass2: combine halves + center + pack.

#define NB 64
#define DD 256
#define MM 100
#define TILE 64
#define NUT 10                 // upper 64x64 tile-pairs of the 4x4 tile grid
#define TRI_PER_B 32896        // D*(D+1)/2
#define NTILE 640              // NB * NUT
#define NMH 50                 // M-half
#define NM2 25                 // fp16x2 m-pairs per half
#define TILE_F (TILE * TILE)

typedef unsigned int u32;
typedef _Float16 f16x2 __attribute__((ext_vector_type(2)));
typedef _Float16 f16x4 __attribute__((ext_vector_type(4)));

__device__ __forceinline__ void tile_coords(int t, int& ti, int& tj) {
    int a = (t >= 4) + (t >= 7) + (t >= 9);
    int s = (a * (9 - a)) >> 1;   // 0,4,7,9
    ti = a;
    tj = t - s + a;
}

// Pass 1: one M-half of one 64x64 tile per block. 256 thr, 4x4 pairs/thread.
extern "C" __global__ void __launch_bounds__(256, 4)
k_partial(const float* __restrict__ f, float* __restrict__ rows,
          _Float16* __restrict__ tiles) {
    __shared__ u32 As[NM2][TILE];   // fp16x2 (m-pair) per row; 6.4 KB
    __shared__ u32 Bs[NM2][TILE];
    const int t = threadIdx.x;
    const int bid = blockIdx.x;       // 0..1279
    const int h = bid & 1;            // M-half
    const int bt = bid >> 1;          // tile id 0..639
    const int b = bt / NUT;
    const int ut = bt % NUT;
    int ti, tj;
    tile_coords(ut, ti, tj);
    const int i0 = ti * TILE, j0 = tj * TILE;
    const float* fb = f + (size_t)b * DD * MM + h * NMH;

    // Stage: f32 pairs -> packed fp16 (cvt_pkrtz), layout [m2][row].
    for (int l = t; l < TILE * NM2; l += 256) {   // 1600
        const int il = l & 63;
        const int m2 = l >> 6;                    // 0..24
        float2 v = *reinterpret_cast<const float2*>(fb + (size_t)(i0 + il) * MM + m2 * 2);
        As[m2][il] = __builtin_bit_cast(u32, __builtin_amdgcn_cvt_pkrtz(v.x, v.y));
        float2 w = *reinterpret_cast<const float2*>(fb + (size_t)(j0 + il) * MM + m2 * 2);
        Bs[m2][il] = __builtin_bit_cast(u32, __builtin_amdgcn_cvt_pkrtz(w.x, w.y));
    }
    __syncthreads();

    const int tix = t & 15, tiy = t >> 4;
    float acc[4][4] = {};   // f32 accumulators

    #pragma unroll 5
    for (int m2 = 0; m2 < NM2; ++m2) {
        uint4 afu = *reinterpret_cast<const uint4*>(&As[m2][tix * 4]);
        uint4 bfu = *reinterpret_cast<const uint4*>(&Bs[m2][tiy * 4]);
        const u32 av[4] = {afu.x, afu.y, afu.z, afu.w};
        const u32 bv[4] = {bfu.x, bfu.y, bfu.z, bfu.w};
        u32 aab[4], aso[4], bab[4], bsg[4];
        #pragma unroll
        for (int q = 0; q < 4; ++q) {
            aab[q] = av[q] & 0x7fff7fffu;                       // |a| packed
            aso[q] = (av[q] & 0x80008000u) | 0x3c003c00u;       // +-1.0 w/ a's sign
        }
        #pragma unroll
        for (int r = 0; r < 4; ++r) {
            bab[r] = bv[r] & 0x7fff7fffu;                       // |b| packed
            bsg[r] = bv[r] & 0x80008000u;                       // b's sign bits
        }
        #pragma unroll
        for (int q = 0; q < 4; ++q) {
            #pragma unroll
            for (int r = 0; r < 4; ++r) {
                u32 so = aso[q] ^ bsg[r];                       // +-1.0 product sign
                f16x2 mn = __builtin_elementwise_min(
                    __builtin_bit_cast(f16x2, aab[q]),
                    __builtin_bit_cast(f16x2, bab[r]));          // v_pk_min_f16
                acc[q][r] = __builtin_amdgcn_fdot2(
                    mn, __builtin_bit_cast(f16x2, so), acc[q][r], false);
            }
        }
    }

    // partial tile -> workspace as f16 [64][64]
    _Float16* tp = tiles + ((size_t)h * NTILE + bt) * TILE_F;
    #pragma unroll
    for (int q = 0; q < 4; ++q) {
        f16x4 hv;
        hv.x = (_Float16)acc[q][0]; hv.y = (_Float16)acc[q][1];
        hv.z = (_Float16)acc[q][2]; hv.w = (_Float16)acc[q][3];
        *reinterpret_cast<f16x4*>(tp + (tix * 4 + q) * TILE + tiy * 4) = hv;
    }

    // row sums (and symmetric col sums for off-diagonal tiles)
    float ra[4], cb[4];
    #pragma unroll
    for (int q = 0; q < 4; ++q)
        ra[q] = (acc[q][0] + acc[q][1]) + (acc[q][2] + acc[q][3]);
    #pragma unroll
    for (int r = 0; r < 4; ++r)
        cb[r] = (acc[0][r] + acc[1][r]) + (acc[2][r] + acc[3][r]);

    __syncthreads();                       // reuse As/Bs as f32 scratch
    float* red  = reinterpret_cast<float*>(&As[0][0]);   // [16][64]
    float* red2 = reinterpret_cast<float*>(&Bs[0][0]);   // [16][64]
    #pragma unroll
    for (int q = 0; q < 4; ++q) red[tiy * 64 + tix * 4 + q] = ra[q];
    #pragma unroll
    for (int r = 0; r < 4; ++r) red2[tix * 64 + tiy * 4 + r] = cb[r];
    __syncthreads();

    if (t < TILE) {
        float s = 0.f;
        #pragma unroll
        for (int w = 0; w < 16; ++w) s += red[w * 64 + t];
        atomicAdd(&rows[b * DD + i0 + t], s);
    } else if (t < 2 * TILE && ti != tj) {
        const int u = t - TILE;
        float s = 0.f;
        #pragma unroll
        for (int w = 0; w < 16; ++w) s += red2[w * 64 + u];
        atomicAdd(&rows[b * DD + j0 + u], s);
    }
}

// Pass 2: combine halves, center, scale, triu-pack. No LDS, coalesced.
extern "C" __global__ void __launch_bounds__(256)
k_finalize(const float* __restrict__ rows, const float* __restrict__ temp,
           const _Float16* __restrict__ tiles, float* __restrict__ out) {
    const int t = threadIdx.x;
    const int bt = blockIdx.x;        // 0..639
    const int b = bt / NUT;
    const int ut = bt % NUT;
    int ti, tj;
    tile_coords(ut, ti, tj);
    const int i0 = ti * TILE, j0 = tj * TILE;
    const int tix = t >> 4, tiy = t & 15;

    const _Float16* t0 = tiles + (size_t)bt * TILE_F;
    const _Float16* t1 = tiles + ((size_t)NTILE + bt) * TILE_F;

    float acc[4][4];
    #pragma unroll
    for (int q = 0; q < 4; ++q) {
        const int off = (tix * 4 + q) * TILE + tiy * 4;
        f16x4 v = *reinterpret_cast<const f16x4*>(t0 + off);
        f16x4 w = *reinterpret_cast<const f16x4*>(t1 + off);
        acc[q][0] = (float)v.x + (float)w.x;
        acc[q][1] = (float)v.y + (float)w.y;
        acc[q][2] = (float)v.z + (float)w.z;
        acc[q][3] = (float)v.w + (float)w.w;
    }

    // NOTE: sign-min identity absorbs the 0.5 -> scale is exp(T) alone.
    const float scale = expf(temp[0]);
    const float inv_d = 1.0f / DD;
    float rloc[4], cloc[4];
    #pragma unroll
    for (int q = 0; q < 4; ++q) rloc[q] = rows[b * DD + i0 + tix * 4 + q];
    #pragma unroll
    for (int r = 0; r < 4; ++r) cloc[r] = rows[b * DD + j0 + tiy * 4 + r];

    float* ob = out + (size_t)b * TRI_PER_B;
    #pragma unroll
    for (int q = 0; q < 4; ++q) {
        const int i = i0 + tix * 4 + q;
        float v[4];
        #pragma unroll
        for (int r = 0; r < 4; ++r)
            v[r] = scale * (acc[q][r] - (rloc[q] + cloc[r]) * inv_d);
        const int j0e = j0 + tiy * 4;
        if (ti != tj) {
            const int off = (i * (2 * DD - i + 1)) / 2 + (j0e - i);
            *reinterpret_cast<float4*>(ob + off) = make_float4(v[0], v[1], v[2], v[3]);
        } else {
            #pragma unroll
            for (int r = 0; r < 4; ++r) {
                const int j = j0e + r;
                if (j >= i) {
                    const int off = (i * (2 * DD - i + 1)) / 2 + (j - i);
                    ob[off] = v[r];
                }
            }
        }
    }
}

extern "C" void kernel_launch(void* const* d_in, const int* in_sizes, int n_in,
                              void* d_out, int out_size, void* d_ws, size_t ws_size,
                              hipStream_t stream) {
    const float* f    = (const float*)d_in[0];
    const float* temp = (const float*)d_in[1];
    float* out  = (float*)d_out;
    float* rows = (float*)d_ws;                           // 64 KB
    _Float16* tiles = (_Float16*)(rows + NB * DD);        // 2*640*4096 f16 = 10.5 MB

    hipMemsetAsync(rows, 0, (size_t)NB * DD * sizeof(float), stream);
    k_partial<<<2 * NTILE, 256, 0, stream>>>(f, rows, tiles);
    k_finalize<<<NTILE, 256, 0, stream>>>(rows, temp, tiles, out);
}